// Round 1
// baseline (925.207 us; speedup 1.0000x reference)
//
#include <hip/hip_runtime.h>

#define Bv 64
#define Lv 4096
#define Dv 64
#define Uv 45
#define UP 48      // padded u
#define NC 16      // score chunks
#define CKK 256    // keys per chunk
#define NSUB 64    // cumsum sub-chunks of 64 rows

// ---- workspace layout (in floats) ----
#define OFF_M    0
#define SZ_M     (Bv*Lv)
#define OFF_QR   (OFF_M + SZ_M)
#define SZ_QR    (Bv*UP*Dv)
#define OFF_PMS  (OFF_QR + SZ_QR)
#define SZ_PMS   (Bv*NC*2*UP)
#define OFF_DEN  (OFF_PMS + SZ_PMS)
#define SZ_DEN   (Bv*2*UP)
#define OFF_PPV  (OFF_DEN + SZ_DEN)
#define SZ_PPV   (Bv*NC*UP*Dv)
#define OFF_CS   (OFF_PPV + SZ_PPV)
#define SZ_CS    (Bv*NSUB*Dv)
#define OFF_CO   (OFF_CS + SZ_CS)
#define SZ_CO    (Bv*NSUB*Dv)
#define OFF_TOP  (OFF_CO + SZ_CO)
#define SZ_TOP   (Bv*Uv)

// ============================================================
// K1: M[b,l] = max_s(q.k_idx) - sum_s(q.k_idx)/L
// XCD-batch swizzle: batch b's 16 blocks land on XCD b%8 (perf heuristic only)
// ============================================================
__global__ __launch_bounds__(256) void k_M(const float* __restrict__ Q,
                                           const float* __restrict__ K,
                                           const int* __restrict__ idx,
                                           float* __restrict__ Mout) {
  int i = blockIdx.x;
  int x = i & 7, q2 = i >> 3;
  int b = (q2 >> 4) * 8 + x;          // 0..63
  int l = (q2 & 15) * 256 + threadIdx.x;
  const float4* qr = (const float4*)(Q + ((size_t)b * Lv + l) * Dv);
  float4 qv[16];
#pragma unroll
  for (int e = 0; e < 16; e++) qv[e] = qr[e];
  const float4* Kb = (const float4*)(K + (size_t)b * Lv * Dv);
  float mx = -3.0e38f, sm = 0.f;
  for (int s = 0; s < Uv; s++) {
    int ki = idx[l * Uv + s];
    const float4* kr = Kb + (size_t)ki * 16;
    float d0 = 0.f, d1 = 0.f, d2 = 0.f, d3 = 0.f;
#pragma unroll
    for (int e = 0; e < 16; e += 4) {
      float4 a0 = kr[e], a1 = kr[e + 1], a2 = kr[e + 2], a3 = kr[e + 3];
      d0 += qv[e].x * a0.x + qv[e].y * a0.y + qv[e].z * a0.z + qv[e].w * a0.w;
      d1 += qv[e+1].x * a1.x + qv[e+1].y * a1.y + qv[e+1].z * a1.z + qv[e+1].w * a1.w;
      d2 += qv[e+2].x * a2.x + qv[e+2].y * a2.y + qv[e+2].z * a2.z + qv[e+2].w * a2.w;
      d3 += qv[e+3].x * a3.x + qv[e+3].y * a3.y + qv[e+3].z * a3.z + qv[e+3].w * a3.w;
    }
    float d = (d0 + d1) + (d2 + d3);
    mx = fmaxf(mx, d);
    sm += d;
  }
  Mout[(size_t)b * Lv + l] = mx - sm * (1.0f / (float)Lv);
}

// ============================================================
// K2: iterative top-45 per batch (ties -> lower index, matches jax)
// ============================================================
__global__ __launch_bounds__(256) void k_topk(const float* __restrict__ M,
                                              int* __restrict__ Mtop) {
  __shared__ float sv[Lv];
  __shared__ float rmax[256];
  __shared__ int rind[256];
  int b = blockIdx.x;
  const float* Mb = M + (size_t)b * Lv;
  for (int i = threadIdx.x; i < Lv; i += 256) sv[i] = Mb[i];
  __syncthreads();
  for (int it = 0; it < Uv; it++) {
    float best = -3.0e38f; int bi = 1 << 30;
    for (int i = threadIdx.x; i < Lv; i += 256) {
      float v = sv[i];
      if (v > best) { best = v; bi = i; }
    }
    rmax[threadIdx.x] = best; rind[threadIdx.x] = bi;
    __syncthreads();
    for (int off = 128; off > 0; off >>= 1) {
      if (threadIdx.x < off) {
        float v2 = rmax[threadIdx.x + off]; int i2 = rind[threadIdx.x + off];
        if (v2 > rmax[threadIdx.x] ||
            (v2 == rmax[threadIdx.x] && i2 < rind[threadIdx.x])) {
          rmax[threadIdx.x] = v2; rind[threadIdx.x] = i2;
        }
      }
      __syncthreads();
    }
    if (threadIdx.x == 0) { Mtop[b * Uv + it] = rind[0]; sv[rind[0]] = -3.0e38f; }
    __syncthreads();
  }
}

// ============================================================
// K3: stage selected queries (pre-scaled by 1/sqrt(D)), pad u to 48 with zeros
// ============================================================
__global__ __launch_bounds__(256) void k_qstage(const float* __restrict__ Q,
                                                const int* __restrict__ Mtop,
                                                float* __restrict__ Qr) {
  int b = blockIdx.x;
  for (int i = threadIdx.x; i < UP * Dv; i += 256) {
    int u = i >> 6, e = i & 63;
    float v = 0.f;
    if (u < Uv) {
      int row = Mtop[b * Uv + u];
      v = Q[((size_t)b * Lv + row) * Dv + e] * 0.125f;
    }
    Qr[((size_t)b * UP + u) * Dv + e] = v;
  }
}

// ---- shared GEMM tile: acc[uu][j] = score(u=ug*8+uu, kk=c*CKK+kg+32*j) ----
#define STAGE_QST(QS, QR, b)                                        \
  for (int i_ = threadIdx.x; i_ < Dv * UP; i_ += blockDim.x) {      \
    int u_ = i_ >> 6, e_ = i_ & 63;                                 \
    QS[e_ * UP + u_] = QR[((size_t)(b) * UP + u_) * Dv + e_];       \
  }

#define SCORE_TILE(ACC, QS, KMAT, b_, c_, ug_, kg_)                                   \
  {                                                                                    \
    const float* Kb_ = (KMAT) + ((size_t)(b_) * Lv + (size_t)(c_) * CKK + (kg_)) * Dv; \
    for (int e = 0; e < Dv; e += 4) {                                                  \
      float qq[4][8];                                                                  \
      _Pragma("unroll")                                                                \
      for (int e2 = 0; e2 < 4; e2++) {                                                 \
        float4 qa = *(const float4*)&(QS)[(e + e2) * UP + (ug_) * 8];                  \
        float4 qb = *(const float4*)&(QS)[(e + e2) * UP + (ug_) * 8 + 4];              \
        qq[e2][0]=qa.x; qq[e2][1]=qa.y; qq[e2][2]=qa.z; qq[e2][3]=qa.w;                \
        qq[e2][4]=qb.x; qq[e2][5]=qb.y; qq[e2][6]=qb.z; qq[e2][7]=qb.w;                \
      }                                                                                \
      _Pragma("unroll")                                                                \
      for (int j = 0; j < 8; j++) {                                                    \
        float4 kv = *(const float4*)(Kb_ + (size_t)(32 * j) * Dv + e);                 \
        _Pragma("unroll")                                                              \
        for (int uu = 0; uu < 8; uu++)                                                 \
          ACC[uu][j] += qq[0][uu]*kv.x + qq[1][uu]*kv.y + qq[2][uu]*kv.z + qq[3][uu]*kv.w; \
      }                                                                                \
    }                                                                                  \
  }

// ============================================================
// K4: per-chunk max and sum-exp partials
// ============================================================
__global__ __launch_bounds__(192) void k_ms(const float* __restrict__ Kmat,
                                            const float* __restrict__ Qr,
                                            float* __restrict__ pms) {
  __shared__ float qsT[Dv * UP];
  int b = blockIdx.x >> 4, c = blockIdx.x & 15;
  STAGE_QST(qsT, Qr, b);
  __syncthreads();
  int t = threadIdx.x, ug = t >> 5, kg = t & 31;
  float acc[8][8];
#pragma unroll
  for (int uu = 0; uu < 8; uu++)
#pragma unroll
    for (int j = 0; j < 8; j++) acc[uu][j] = 0.f;
  SCORE_TILE(acc, qsT, Kmat, b, c, ug, kg);
#pragma unroll
  for (int uu = 0; uu < 8; uu++) {
    float m = acc[uu][0];
#pragma unroll
    for (int j = 1; j < 8; j++) m = fmaxf(m, acc[uu][j]);
#pragma unroll
    for (int off = 1; off < 32; off <<= 1) m = fmaxf(m, __shfl_xor(m, off));
    float s = 0.f;
#pragma unroll
    for (int j = 0; j < 8; j++) s += __expf(acc[uu][j] - m);
#pragma unroll
    for (int off = 1; off < 32; off <<= 1) s += __shfl_xor(s, off);
    if (kg == 0) {
      pms[(((size_t)b * NC + c) * 2 + 0) * UP + ug * 8 + uu] = m;
      pms[(((size_t)b * NC + c) * 2 + 1) * UP + ug * 8 + uu] = s;
    }
  }
}

// ============================================================
// K5: merge chunk partials -> global max + 1/denominator
// ============================================================
__global__ __launch_bounds__(64) void k_den(const float* __restrict__ pms,
                                            float* __restrict__ den) {
  int b = blockIdx.x, u = threadIdx.x;
  if (u >= UP) return;
  float mx = -3.0e38f;
  for (int c = 0; c < NC; c++)
    mx = fmaxf(mx, pms[(((size_t)b * NC + c) * 2 + 0) * UP + u]);
  float d = 0.f;
  for (int c = 0; c < NC; c++)
    d += pms[(((size_t)b * NC + c) * 2 + 1) * UP + u] *
         __expf(pms[(((size_t)b * NC + c) * 2 + 0) * UP + u] - mx);
  den[(size_t)b * 2 * UP + u] = mx;
  den[(size_t)b * 2 * UP + UP + u] = 1.f / d;
}

// ============================================================
// K6: recompute scores, apply softmax weights, PV partial per chunk
// ============================================================
__global__ __launch_bounds__(192) void k_pv(const float* __restrict__ Kmat,
                                            const float* __restrict__ V,
                                            const float* __restrict__ Qr,
                                            const float* __restrict__ den,
                                            float* __restrict__ ppv) {
  __shared__ float qsT[Dv * UP];
  __shared__ float wl[UP * CKK];   // 48KB weights
  int b = blockIdx.x >> 4, c = blockIdx.x & 15;
  STAGE_QST(qsT, Qr, b);
  __syncthreads();
  int t = threadIdx.x, ug = t >> 5, kg = t & 31;
  {
    float acc[8][8];
#pragma unroll
    for (int uu = 0; uu < 8; uu++)
#pragma unroll
      for (int j = 0; j < 8; j++) acc[uu][j] = 0.f;
    SCORE_TILE(acc, qsT, Kmat, b, c, ug, kg);
#pragma unroll
    for (int uu = 0; uu < 8; uu++) {
      float mx = den[(size_t)b * 2 * UP + ug * 8 + uu];
      float iv = den[(size_t)b * 2 * UP + UP + ug * 8 + uu];
#pragma unroll
      for (int j = 0; j < 8; j++)
        wl[(ug * 8 + uu) * CKK + kg + 32 * j] = __expf(acc[uu][j] - mx) * iv;
    }
  }
  __syncthreads();
  // phase B: wave w handles 16 u rows, lane = d
  int w = t >> 6, lane = t & 63;
  float acc2[16];
#pragma unroll
  for (int uu = 0; uu < 16; uu++) acc2[uu] = 0.f;
  const float* Vb = V + ((size_t)b * Lv + (size_t)c * CKK) * Dv;
  for (int k4 = 0; k4 < CKK; k4 += 4) {
    float v0 = Vb[(size_t)(k4 + 0) * Dv + lane];
    float v1 = Vb[(size_t)(k4 + 1) * Dv + lane];
    float v2 = Vb[(size_t)(k4 + 2) * Dv + lane];
    float v3 = Vb[(size_t)(k4 + 3) * Dv + lane];
#pragma unroll
    for (int uu = 0; uu < 16; uu++) {
      float4 w4 = *(const float4*)&wl[(w * 16 + uu) * CKK + k4];
      acc2[uu] += w4.x * v0 + w4.y * v1 + w4.z * v2 + w4.w * v3;
    }
  }
#pragma unroll
  for (int uu = 0; uu < 16; uu++)
    ppv[(((size_t)b * NC + c) * UP + w * 16 + uu) * Dv + lane] = acc2[uu];
}

// ============================================================
// cumsum over L (3-kernel chunked scan), sub-chunks of 64 rows
// ============================================================
__global__ __launch_bounds__(256) void k_cs1(const float* __restrict__ V,
                                             float* __restrict__ cs) {
  int b = blockIdx.x >> 4, c4 = blockIdx.x & 15;
  int g = threadIdx.x >> 6, d = threadIdx.x & 63;
  int sub = c4 * 4 + g;
  const float* Vb = V + ((size_t)b * Lv + sub * 64) * Dv + d;
  float acc = 0.f;
  for (int r = 0; r < 64; r++) acc += Vb[(size_t)r * Dv];
  cs[((size_t)b * NSUB + sub) * Dv + d] = acc;
}

__global__ __launch_bounds__(64) void k_cs2(const float* __restrict__ cs,
                                            float* __restrict__ co) {
  int b = blockIdx.x, d = threadIdx.x;
  float run = 0.f;
  for (int s = 0; s < NSUB; s++) {
    co[((size_t)b * NSUB + s) * Dv + d] = run;
    run += cs[((size_t)b * NSUB + s) * Dv + d];
  }
}

__global__ __launch_bounds__(256) void k_cs3(const float* __restrict__ V,
                                             const float* __restrict__ co,
                                             float* __restrict__ out) {
  int b = blockIdx.x >> 4, c4 = blockIdx.x & 15;
  int g = threadIdx.x >> 6, d = threadIdx.x & 63;
  int sub = c4 * 4 + g;
  const float* Vb = V + ((size_t)b * Lv + sub * 64) * Dv + d;
  float* Ob = out + ((size_t)b * Lv + sub * 64) * Dv + d;
  float acc = co[((size_t)b * NSUB + sub) * Dv + d];
  for (int r = 0; r < 64; r++) {
    acc += Vb[(size_t)r * Dv];
    Ob[(size_t)r * Dv] = acc;
  }
}

// ============================================================
// K10: merge PV partials, scatter into output rows
// ============================================================
__global__ __launch_bounds__(64) void k_upd(const float* __restrict__ ppv,
                                            const int* __restrict__ Mtop,
                                            float* __restrict__ out) {
  int b = blockIdx.x / Uv, u = blockIdx.x % Uv;
  int d = threadIdx.x;
  float s = 0.f;
  for (int c = 0; c < NC; c++)
    s += ppv[(((size_t)b * NC + c) * UP + u) * Dv + d];
  int row = Mtop[b * Uv + u];
  out[((size_t)b * Lv + row) * Dv + d] = s;
}

extern "C" void kernel_launch(void* const* d_in, const int* in_sizes, int n_in,
                              void* d_out, int out_size, void* d_ws, size_t ws_size,
                              hipStream_t stream) {
  (void)in_sizes; (void)n_in; (void)out_size; (void)ws_size;
  const float* Q = (const float*)d_in[0];
  const float* K = (const float*)d_in[1];
  const float* V = (const float*)d_in[2];
  const int* idx = (const int*)d_in[3];
  float* out = (float*)d_out;
  float* wsf = (float*)d_ws;
  float* M   = wsf + OFF_M;
  float* Qr  = wsf + OFF_QR;
  float* pms = wsf + OFF_PMS;
  float* den = wsf + OFF_DEN;
  float* ppv = wsf + OFF_PPV;
  float* cs  = wsf + OFF_CS;
  float* co  = wsf + OFF_CO;
  int* top   = (int*)(wsf + OFF_TOP);

  k_M<<<1024, 256, 0, stream>>>(Q, K, idx, M);
  k_topk<<<Bv, 256, 0, stream>>>(M, top);
  k_qstage<<<Bv, 256, 0, stream>>>(Q, top, Qr);
  k_ms<<<Bv * NC, 192, 0, stream>>>(K, Qr, pms);
  k_den<<<Bv, 64, 0, stream>>>(pms, den);
  k_pv<<<Bv * NC, 192, 0, stream>>>(K, V, Qr, den, ppv);
  k_cs1<<<1024, 256, 0, stream>>>(V, cs);
  k_cs2<<<Bv, 64, 0, stream>>>(cs, co);
  k_cs3<<<1024, 256, 0, stream>>>(V, co, out);
  k_upd<<<Bv * Uv, 64, 0, stream>>>(ppv, top, out);
}

// Round 3
// 630.333 us; speedup vs baseline: 1.4678x; 1.4678x over previous
//
#include <hip/hip_runtime.h>

#define Bv 64
#define Lv 4096
#define Dv 64
#define Uv 45
#define UP 48      // padded u
#define NC 16      // score chunks
#define CKK 256    // keys per chunk
#define NSUB 64    // cumsum sub-chunks of 64 rows

// ---- workspace layout (in floats) ----
#define OFF_M    0
#define SZ_M     (Bv*Lv)
#define OFF_QR   (OFF_M + SZ_M)
#define SZ_QR    (Bv*UP*Dv)
#define OFF_PMS  (OFF_QR + SZ_QR)
#define SZ_PMS   (Bv*NC*2*UP)
#define OFF_DEN  (OFF_PMS + SZ_PMS)
#define SZ_DEN   (Bv*2*UP)
#define OFF_PPV  (OFF_DEN + SZ_DEN)
#define SZ_PPV   (Bv*NC*UP*Dv)
#define OFF_CS   (OFF_PPV + SZ_PPV)
#define SZ_CS    (Bv*NSUB*Dv)
#define OFF_CO   (OFF_CS + SZ_CS)
#define SZ_CO    (Bv*NSUB*Dv)
#define OFF_TOP  (OFF_CO + SZ_CO)
#define SZ_TOP   (Bv*Uv)

// ============================================================
// K1: M[b,l] = max_s(q.k_idx) - sum_s(q.k_idx)/L
// 16 lanes per l (lane holds float4 of q); idx staged in LDS;
// batch<->XCD phase-locked swizzle: XCD x runs batch x, x+8, ...
// ============================================================
__global__ __launch_bounds__(256) void k_M(const float* __restrict__ Q,
                                           const float* __restrict__ K,
                                           const int* __restrict__ idx,
                                           float* __restrict__ Mout) {
  __shared__ int sidx[16 * Uv];
  int i = blockIdx.x;
  int x = i & 7, j = i >> 3;
  int b = x + 8 * (j >> 8);      // XCD x sees batches x, x+8, ... sequentially
  int w = j & 255;               // within-batch block index (16 l's each)
  int t = threadIdx.x;
  for (int p = t; p < 16 * Uv; p += 256) sidx[p] = idx[w * (16 * Uv) + p];
  int g = t >> 4, lane = t & 15;
  int l = w * 16 + g;
  float4 qv = *(const float4*)(Q + ((size_t)b * Lv + l) * Dv + lane * 4);
  const float* Kb = K + (size_t)b * Lv * Dv + lane * 4;
  __syncthreads();
  float mx = -3.0e38f, sm = 0.f;
#pragma unroll 5
  for (int s = 0; s < Uv; s++) {
    int ki = sidx[g * Uv + s];
    float4 kv = *(const float4*)(Kb + (size_t)ki * Dv);
    float d = qv.x * kv.x + qv.y * kv.y + qv.z * kv.z + qv.w * kv.w;
    d += __shfl_xor(d, 1);
    d += __shfl_xor(d, 2);
    d += __shfl_xor(d, 4);
    d += __shfl_xor(d, 8);
    mx = fmaxf(mx, d);
    sm += d;
  }
  if (lane == 0) Mout[(size_t)b * Lv + l] = mx - sm * (1.0f / (float)Lv);
}

// ============================================================
// K2: iterative top-45 per batch (ties -> lower index, matches jax)
// ============================================================
__global__ __launch_bounds__(256) void k_topk(const float* __restrict__ M,
                                              int* __restrict__ Mtop) {
  __shared__ float sv[Lv];
  __shared__ float rmax[256];
  __shared__ int rind[256];
  int b = blockIdx.x;
  const float* Mb = M + (size_t)b * Lv;
  for (int i = threadIdx.x; i < Lv; i += 256) sv[i] = Mb[i];
  __syncthreads();
  for (int it = 0; it < Uv; it++) {
    float best = -3.0e38f; int bi = 1 << 30;
    for (int i = threadIdx.x; i < Lv; i += 256) {
      float v = sv[i];
      if (v > best) { best = v; bi = i; }
    }
    rmax[threadIdx.x] = best; rind[threadIdx.x] = bi;
    __syncthreads();
    for (int off = 128; off > 0; off >>= 1) {
      if (threadIdx.x < off) {
        float v2 = rmax[threadIdx.x + off]; int i2 = rind[threadIdx.x + off];
        if (v2 > rmax[threadIdx.x] ||
            (v2 == rmax[threadIdx.x] && i2 < rind[threadIdx.x])) {
          rmax[threadIdx.x] = v2; rind[threadIdx.x] = i2;
        }
      }
      __syncthreads();
    }
    if (threadIdx.x == 0) { Mtop[b * Uv + it] = rind[0]; sv[rind[0]] = -3.0e38f; }
    __syncthreads();
  }
}

// ============================================================
// K3: stage selected queries (pre-scaled by 1/sqrt(D)), pad u to 48 with zeros
// ============================================================
__global__ __launch_bounds__(256) void k_qstage(const float* __restrict__ Q,
                                                const int* __restrict__ Mtop,
                                                float* __restrict__ Qr) {
  int b = blockIdx.x;
  for (int i = threadIdx.x; i < UP * Dv; i += 256) {
    int u = i >> 6, e = i & 63;
    float v = 0.f;
    if (u < Uv) {
      int row = Mtop[b * Uv + u];
      v = Q[((size_t)b * Lv + row) * Dv + e] * 0.125f;
    }
    Qr[((size_t)b * UP + u) * Dv + e] = v;
  }
}

// ---- shared GEMM tile: acc[uu][j] = score(u=ug*8+uu, kk=c*CKK+kg+32*j) ----
#define STAGE_QST(QS, QR, b)                                        \
  for (int i_ = threadIdx.x; i_ < Dv * UP; i_ += blockDim.x) {      \
    int u_ = i_ >> 6, e_ = i_ & 63;                                 \
    QS[e_ * UP + u_] = QR[((size_t)(b) * UP + u_) * Dv + e_];       \
  }

#define SCORE_TILE(ACC, QS, KMAT, b_, c_, ug_, kg_)                                   \
  {                                                                                    \
    const float* Kb_ = (KMAT) + ((size_t)(b_) * Lv + (size_t)(c_) * CKK + (kg_)) * Dv; \
    for (int e = 0; e < Dv; e += 4) {                                                  \
      float qq[4][8];                                                                  \
      _Pragma("unroll")                                                                \
      for (int e2 = 0; e2 < 4; e2++) {                                                 \
        float4 qa = *(const float4*)&(QS)[(e + e2) * UP + (ug_) * 8];                  \
        float4 qb = *(const float4*)&(QS)[(e + e2) * UP + (ug_) * 8 + 4];              \
        qq[e2][0]=qa.x; qq[e2][1]=qa.y; qq[e2][2]=qa.z; qq[e2][3]=qa.w;                \
        qq[e2][4]=qb.x; qq[e2][5]=qb.y; qq[e2][6]=qb.z; qq[e2][7]=qb.w;                \
      }                                                                                \
      _Pragma("unroll")                                                                \
      for (int j = 0; j < 8; j++) {                                                    \
        float4 kv = *(const float4*)(Kb_ + (size_t)(32 * j) * Dv + e);                 \
        _Pragma("unroll")                                                              \
        for (int uu = 0; uu < 8; uu++)                                                 \
          ACC[uu][j] += qq[0][uu]*kv.x + qq[1][uu]*kv.y + qq[2][uu]*kv.z + qq[3][uu]*kv.w; \
      }                                                                                  \
    }                                                                                  \
  }

// ============================================================
// K4: per-chunk max and sum-exp partials
// ============================================================
__global__ __launch_bounds__(192) void k_ms(const float* __restrict__ Kmat,
                                            const float* __restrict__ Qr,
                                            float* __restrict__ pms) {
  __shared__ float qsT[Dv * UP];
  int b = blockIdx.x >> 4, c = blockIdx.x & 15;
  STAGE_QST(qsT, Qr, b);
  __syncthreads();
  int t = threadIdx.x, ug = t >> 5, kg = t & 31;
  float acc[8][8];
#pragma unroll
  for (int uu = 0; uu < 8; uu++)
#pragma unroll
    for (int j = 0; j < 8; j++) acc[uu][j] = 0.f;
  SCORE_TILE(acc, qsT, Kmat, b, c, ug, kg);
#pragma unroll
  for (int uu = 0; uu < 8; uu++) {
    float m = acc[uu][0];
#pragma unroll
    for (int j = 1; j < 8; j++) m = fmaxf(m, acc[uu][j]);
#pragma unroll
    for (int off = 1; off < 32; off <<= 1) m = fmaxf(m, __shfl_xor(m, off));
    float s = 0.f;
#pragma unroll
    for (int j = 0; j < 8; j++) s += __expf(acc[uu][j] - m);
#pragma unroll
    for (int off = 1; off < 32; off <<= 1) s += __shfl_xor(s, off);
    if (kg == 0) {
      pms[(((size_t)b * NC + c) * 2 + 0) * UP + ug * 8 + uu] = m;
      pms[(((size_t)b * NC + c) * 2 + 1) * UP + ug * 8 + uu] = s;
    }
  }
}

// ============================================================
// K5: merge chunk partials -> global max + 1/denominator
// ============================================================
__global__ __launch_bounds__(64) void k_den(const float* __restrict__ pms,
                                            float* __restrict__ den) {
  int b = blockIdx.x, u = threadIdx.x;
  if (u >= UP) return;
  float mx = -3.0e38f;
  for (int c = 0; c < NC; c++)
    mx = fmaxf(mx, pms[(((size_t)b * NC + c) * 2 + 0) * UP + u]);
  float d = 0.f;
  for (int c = 0; c < NC; c++)
    d += pms[(((size_t)b * NC + c) * 2 + 1) * UP + u] *
         __expf(pms[(((size_t)b * NC + c) * 2 + 0) * UP + u] - mx);
  den[(size_t)b * 2 * UP + u] = mx;
  den[(size_t)b * 2 * UP + UP + u] = 1.f / d;
}

// ============================================================
// K6: recompute scores, apply softmax weights, PV partial per chunk
// ============================================================
__global__ __launch_bounds__(192) void k_pv(const float* __restrict__ Kmat,
                                            const float* __restrict__ V,
                                            const float* __restrict__ Qr,
                                            const float* __restrict__ den,
                                            float* __restrict__ ppv) {
  __shared__ float qsT[Dv * UP];
  __shared__ float wl[UP * CKK];   // 48KB weights
  int b = blockIdx.x >> 4, c = blockIdx.x & 15;
  STAGE_QST(qsT, Qr, b);
  __syncthreads();
  int t = threadIdx.x, ug = t >> 5, kg = t & 31;
  {
    float acc[8][8];
#pragma unroll
    for (int uu = 0; uu < 8; uu++)
#pragma unroll
      for (int j = 0; j < 8; j++) acc[uu][j] = 0.f;
    SCORE_TILE(acc, qsT, Kmat, b, c, ug, kg);
#pragma unroll
    for (int uu = 0; uu < 8; uu++) {
      float mx = den[(size_t)b * 2 * UP + ug * 8 + uu];
      float iv = den[(size_t)b * 2 * UP + UP + ug * 8 + uu];
#pragma unroll
      for (int j = 0; j < 8; j++)
        wl[(ug * 8 + uu) * CKK + kg + 32 * j] = __expf(acc[uu][j] - mx) * iv;
    }
  }
  __syncthreads();
  // phase B: wave w handles 16 u rows, lane = d
  int w = t >> 6, lane = t & 63;
  float acc2[16];
#pragma unroll
  for (int uu = 0; uu < 16; uu++) acc2[uu] = 0.f;
  const float* Vb = V + ((size_t)b * Lv + (size_t)c * CKK) * Dv;
  for (int k4 = 0; k4 < CKK; k4 += 4) {
    float v0 = Vb[(size_t)(k4 + 0) * Dv + lane];
    float v1 = Vb[(size_t)(k4 + 1) * Dv + lane];
    float v2 = Vb[(size_t)(k4 + 2) * Dv + lane];
    float v3 = Vb[(size_t)(k4 + 3) * Dv + lane];
#pragma unroll
    for (int uu = 0; uu < 16; uu++) {
      float4 w4 = *(const float4*)&wl[(w * 16 + uu) * CKK + k4];
      acc2[uu] += w4.x * v0 + w4.y * v1 + w4.z * v2 + w4.w * v3;
    }
  }
#pragma unroll
  for (int uu = 0; uu < 16; uu++)
    ppv[(((size_t)b * NC + c) * UP + w * 16 + uu) * Dv + lane] = acc2[uu];
}

// ============================================================
// cumsum over L (3-kernel chunked scan), sub-chunks of 64 rows
// ============================================================
__global__ __launch_bounds__(256) void k_cs1(const float* __restrict__ V,
                                             float* __restrict__ cs) {
  int b = blockIdx.x >> 4, c4 = blockIdx.x & 15;
  int g = threadIdx.x >> 6, d = threadIdx.x & 63;
  int sub = c4 * 4 + g;
  const float* Vb = V + ((size_t)b * Lv + sub * 64) * Dv + d;
  float acc = 0.f;
  for (int r = 0; r < 64; r++) acc += Vb[(size_t)r * Dv];
  cs[((size_t)b * NSUB + sub) * Dv + d] = acc;
}

__global__ __launch_bounds__(64) void k_cs2(const float* __restrict__ cs,
                                            float* __restrict__ co) {
  int b = blockIdx.x, d = threadIdx.x;
  float run = 0.f;
  for (int s = 0; s < NSUB; s++) {
    co[((size_t)b * NSUB + s) * Dv + d] = run;
    run += cs[((size_t)b * NSUB + s) * Dv + d];
  }
}

__global__ __launch_bounds__(256) void k_cs3(const float* __restrict__ V,
                                             const float* __restrict__ co,
                                             float* __restrict__ out) {
  int b = blockIdx.x >> 4, c4 = blockIdx.x & 15;
  int g = threadIdx.x >> 6, d = threadIdx.x & 63;
  int sub = c4 * 4 + g;
  const float* Vb = V + ((size_t)b * Lv + sub * 64) * Dv + d;
  float* Ob = out + ((size_t)b * Lv + sub * 64) * Dv + d;
  float acc = co[((size_t)b * NSUB + sub) * Dv + d];
  for (int r = 0; r < 64; r++) {
    acc += Vb[(size_t)r * Dv];
    Ob[(size_t)r * Dv] = acc;
  }
}

// ============================================================
// K10: merge PV partials, scatter into output rows
// ============================================================
__global__ __launch_bounds__(64) void k_upd(const float* __restrict__ ppv,
                                            const int* __restrict__ Mtop,
                                            float* __restrict__ out) {
  int b = blockIdx.x / Uv, u = blockIdx.x % Uv;
  int d = threadIdx.x;
  float s = 0.f;
  for (int c = 0; c < NC; c++)
    s += ppv[(((size_t)b * NC + c) * UP + u) * Dv + d];
  int row = Mtop[b * Uv + u];
  out[((size_t)b * Lv + row) * Dv + d] = s;
}

extern "C" void kernel_launch(void* const* d_in, const int* in_sizes, int n_in,
                              void* d_out, int out_size, void* d_ws, size_t ws_size,
                              hipStream_t stream) {
  (void)in_sizes; (void)n_in; (void)out_size; (void)ws_size;
  const float* Q = (const float*)d_in[0];
  const float* K = (const float*)d_in[1];
  const float* V = (const float*)d_in[2];
  const int* idx = (const int*)d_in[3];
  float* out = (float*)d_out;
  float* wsf = (float*)d_ws;
  float* M   = wsf + OFF_M;
  float* Qr  = wsf + OFF_QR;
  float* pms = wsf + OFF_PMS;
  float* den = wsf + OFF_DEN;
  float* ppv = wsf + OFF_PPV;
  float* cs  = wsf + OFF_CS;
  float* co  = wsf + OFF_CO;
  int* top   = (int*)(wsf + OFF_TOP);

  k_M<<<16384, 256, 0, stream>>>(Q, K, idx, M);
  k_topk<<<Bv, 256, 0, stream>>>(M, top);
  k_qstage<<<Bv, 256, 0, stream>>>(Q, top, Qr);
  k_ms<<<Bv * NC, 192, 0, stream>>>(K, Qr, pms);
  k_den<<<Bv, 64, 0, stream>>>(pms, den);
  k_pv<<<Bv * NC, 192, 0, stream>>>(K, V, Qr, den, ppv);
  k_cs1<<<1024, 256, 0, stream>>>(V, cs);
  k_cs2<<<Bv, 64, 0, stream>>>(cs, co);
  k_cs3<<<1024, 256, 0, stream>>>(V, co, out);
  k_upd<<<Bv * Uv, 64, 0, stream>>>(ppv, top, out);
}

// Round 5
// 596.283 us; speedup vs baseline: 1.5516x; 1.0571x over previous
//
#include <hip/hip_runtime.h>

#define Bv 64
#define Lv 4096
#define Dv 64
#define Uv 45
#define UP 48      // padded u
#define NC 16      // score chunks
#define CKK 256    // keys per chunk
#define NSUB 64    // cumsum sub-chunks of 64 rows

// ---- workspace layout (in floats) ----
#define OFF_M    0
#define SZ_M     (Bv*Lv)
#define OFF_QR   (OFF_M + SZ_M)
#define SZ_QR    (Bv*UP*Dv)
#define OFF_PMS  (OFF_QR + SZ_QR)
#define SZ_PMS   (Bv*NC*2*UP)
#define OFF_DEN  (OFF_PMS + SZ_PMS)
#define SZ_DEN   (Bv*2*UP)
#define OFF_PPV  (OFF_DEN + SZ_DEN)
#define SZ_PPV   (Bv*NC*UP*Dv)
#define OFF_CS   (OFF_PPV + SZ_PPV)
#define SZ_CS    (Bv*NSUB*Dv)
#define OFF_TOP  (OFF_CS + SZ_CS)
#define SZ_TOP   (Bv*Uv)

// ============================================================
// K1: M[b,l] = max_s(q.k_idx) - sum_s(q.k_idx)/L
// w=8 lanes per row (2 float4 of q each, 3-shfl reduce); idx in LDS.
// XCD phase-lock: XCD x runs batches x, x+8, ... ; full occupancy
// keeps 2 batches (4MB ~ L2) resident per XCD.
// ============================================================
__global__ __launch_bounds__(256) void k_M(const float* __restrict__ Q,
                                           const float* __restrict__ K,
                                           const int* __restrict__ idx,
                                           float* __restrict__ Mout) {
  __shared__ int sidx[32 * Uv];
  int i = blockIdx.x;
  int x = i & 7, j = i >> 3;
  int b = x + 8 * (j >> 7);      // XCD x sees batches x, x+8, ...
  int w = j & 127;               // within-batch block index (32 rows each)
  int t = threadIdx.x;
  for (int p = t; p < 32 * Uv; p += 256) sidx[p] = idx[(w * 32) * Uv + p];
  int g = t >> 3, lane = t & 7;
  int l = w * 32 + g;
  const float4* qr = (const float4*)(Q + ((size_t)b * Lv + l) * Dv + lane * 8);
  float4 q0 = qr[0], q1 = qr[1];
  const char* Kb = (const char*)(K + (size_t)b * Lv * Dv) + lane * 32;
  __syncthreads();
  float mx = -3.0e38f, sm = 0.f;
#pragma unroll 3
  for (int s = 0; s < Uv; s++) {
    int ki = sidx[g * Uv + s];
    const float4* kr = (const float4*)(Kb + (size_t)ki * 256);
    float4 k0 = kr[0], k1 = kr[1];
    float d = q0.x * k0.x + q0.y * k0.y + q0.z * k0.z + q0.w * k0.w
            + q1.x * k1.x + q1.y * k1.y + q1.z * k1.z + q1.w * k1.w;
    d += __shfl_xor(d, 1);
    d += __shfl_xor(d, 2);
    d += __shfl_xor(d, 4);
    mx = fmaxf(mx, d);
    sm += d;
  }
  if (lane == 0) Mout[(size_t)b * Lv + l] = mx - sm * (1.0f / (float)Lv);
}

// ============================================================
// K2: top-45 per batch, register-resident, 1024 threads.
// Ties -> lower index (matches jax). Fused qstage epilogue.
// ============================================================
__global__ __launch_bounds__(1024) void k_topk(const float* __restrict__ M,
                                               const float* __restrict__ Q,
                                               int* __restrict__ Mtop,
                                               float* __restrict__ Qr) {
  __shared__ float wv[16];
  __shared__ int wi[16];
  __shared__ float win_v;
  __shared__ int win_i;
  __shared__ int list[Uv];
  int b = blockIdx.x;
  int t = threadIdx.x;
  const float* Mb = M + (size_t)b * Lv;
  float r0 = Mb[t], r1 = Mb[t + 1024], r2 = Mb[t + 2048], r3 = Mb[t + 3072];
  int wave = t >> 6, lane = t & 63;
  for (int it = 0; it < Uv; it++) {
    // local best of 4 (ascending idx scan, strict > keeps lowest idx)
    float bv = r0; int bi = t;
    if (r1 > bv) { bv = r1; bi = t + 1024; }
    if (r2 > bv) { bv = r2; bi = t + 2048; }
    if (r3 > bv) { bv = r3; bi = t + 3072; }
    // wave butterfly (64 lanes)
#pragma unroll
    for (int off = 1; off < 64; off <<= 1) {
      float v2 = __shfl_xor(bv, off);
      int i2 = __shfl_xor(bi, off);
      if (v2 > bv || (v2 == bv && i2 < bi)) { bv = v2; bi = i2; }
    }
    if (lane == 0) { wv[wave] = bv; wi[wave] = bi; }
    __syncthreads();
    if (t < 64) {
      float cv = (lane < 16) ? wv[lane] : -3.0e38f;
      int ci = (lane < 16) ? wi[lane] : (1 << 30);
#pragma unroll
      for (int off = 1; off < 16; off <<= 1) {
        float v2 = __shfl_xor(cv, off);
        int i2 = __shfl_xor(ci, off);
        if (v2 > cv || (v2 == cv && i2 < ci)) { cv = v2; ci = i2; }
      }
      if (lane == 0) { win_v = cv; win_i = ci; list[it] = ci; }
    }
    __syncthreads();
    int wn = win_i;
    if ((wn & 1023) == t) {
      int c = wn >> 10;
      if (c == 0) r0 = -3.0e38f;
      else if (c == 1) r1 = -3.0e38f;
      else if (c == 2) r2 = -3.0e38f;
      else r3 = -3.0e38f;
    }
    __syncthreads();
  }
  // write Mtop + fused qstage (pre-scaled by 1/sqrt(D)=0.125, pad to UP)
  if (t < Uv) Mtop[b * Uv + t] = list[t];
  for (int p = t; p < UP * Dv; p += 1024) {
    int u = p >> 6, e = p & 63;
    float v = 0.f;
    if (u < Uv) {
      int row = list[u];
      v = Q[((size_t)b * Lv + row) * Dv + e] * 0.125f;
    }
    Qr[((size_t)b * UP + u) * Dv + e] = v;
  }
}

// ---- shared GEMM tile: acc[uu][j] = score(u=ug*8+uu, kk=c*CKK+kg+32*j) ----
#define STAGE_QST(QS, QR, b)                                        \
  for (int i_ = threadIdx.x; i_ < Dv * UP; i_ += blockDim.x) {      \
    int u_ = i_ >> 6, e_ = i_ & 63;                                 \
    QS[e_ * UP + u_] = QR[((size_t)(b) * UP + u_) * Dv + e_];       \
  }

#define SCORE_TILE(ACC, QS, KMAT, b_, c_, ug_, kg_)                                   \
  {                                                                                    \
    const float* Kb_ = (KMAT) + ((size_t)(b_) * Lv + (size_t)(c_) * CKK + (kg_)) * Dv; \
    for (int e = 0; e < Dv; e += 4) {                                                  \
      float qq[4][8];                                                                  \
      _Pragma("unroll")                                                                \
      for (int e2 = 0; e2 < 4; e2++) {                                                 \
        float4 qa = *(const float4*)&(QS)[(e + e2) * UP + (ug_) * 8];                  \
        float4 qb = *(const float4*)&(QS)[(e + e2) * UP + (ug_) * 8 + 4];              \
        qq[e2][0]=qa.x; qq[e2][1]=qa.y; qq[e2][2]=qa.z; qq[e2][3]=qa.w;                \
        qq[e2][4]=qb.x; qq[e2][5]=qb.y; qq[e2][6]=qb.z; qq[e2][7]=qb.w;                \
      }                                                                                \
      _Pragma("unroll")                                                                \
      for (int j = 0; j < 8; j++) {                                                    \
        float4 kv = *(const float4*)(Kb_ + (size_t)(32 * j) * Dv + e);                 \
        _Pragma("unroll")                                                              \
        for (int uu = 0; uu < 8; uu++)                                                 \
          ACC[uu][j] += qq[0][uu]*kv.x + qq[1][uu]*kv.y + qq[2][uu]*kv.z + qq[3][uu]*kv.w; \
      }                                                                                  \
    }                                                                                  \
  }

// ============================================================
// K4: per-chunk max and sum-exp partials
// ============================================================
__global__ __launch_bounds__(192) void k_ms(const float* __restrict__ Kmat,
                                            const float* __restrict__ Qr,
                                            float* __restrict__ pms) {
  __shared__ float qsT[Dv * UP];
  int b = blockIdx.x >> 4, c = blockIdx.x & 15;
  STAGE_QST(qsT, Qr, b);
  __syncthreads();
  int t = threadIdx.x, ug = t >> 5, kg = t & 31;
  float acc[8][8];
#pragma unroll
  for (int uu = 0; uu < 8; uu++)
#pragma unroll
    for (int j = 0; j < 8; j++) acc[uu][j] = 0.f;
  SCORE_TILE(acc, qsT, Kmat, b, c, ug, kg);
#pragma unroll
  for (int uu = 0; uu < 8; uu++) {
    float m = acc[uu][0];
#pragma unroll
    for (int j = 1; j < 8; j++) m = fmaxf(m, acc[uu][j]);
#pragma unroll
    for (int off = 1; off < 32; off <<= 1) m = fmaxf(m, __shfl_xor(m, off));
    float s = 0.f;
#pragma unroll
    for (int j = 0; j < 8; j++) s += __expf(acc[uu][j] - m);
#pragma unroll
    for (int off = 1; off < 32; off <<= 1) s += __shfl_xor(s, off);
    if (kg == 0) {
      pms[(((size_t)b * NC + c) * 2 + 0) * UP + ug * 8 + uu] = m;
      pms[(((size_t)b * NC + c) * 2 + 1) * UP + ug * 8 + uu] = s;
    }
  }
}

// ============================================================
// K5: merge chunk partials -> global max + 1/denominator
// ============================================================
__global__ __launch_bounds__(64) void k_den(const float* __restrict__ pms,
                                            float* __restrict__ den) {
  int b = blockIdx.x, u = threadIdx.x;
  if (u >= UP) return;
  float mx = -3.0e38f;
  for (int c = 0; c < NC; c++)
    mx = fmaxf(mx, pms[(((size_t)b * NC + c) * 2 + 0) * UP + u]);
  float d = 0.f;
  for (int c = 0; c < NC; c++)
    d += pms[(((size_t)b * NC + c) * 2 + 1) * UP + u] *
         __expf(pms[(((size_t)b * NC + c) * 2 + 0) * UP + u] - mx);
  den[(size_t)b * 2 * UP + u] = mx;
  den[(size_t)b * 2 * UP + UP + u] = 1.f / d;
}

// ============================================================
// K6: recompute scores, apply softmax weights, PV partial per chunk
// ============================================================
__global__ __launch_bounds__(192) void k_pv(const float* __restrict__ Kmat,
                                            const float* __restrict__ V,
                                            const float* __restrict__ Qr,
                                            const float* __restrict__ den,
                                            float* __restrict__ ppv) {
  __shared__ float qsT[Dv * UP];
  __shared__ float wl[UP * CKK];   // 48KB weights
  int b = blockIdx.x >> 4, c = blockIdx.x & 15;
  STAGE_QST(qsT, Qr, b);
  __syncthreads();
  int t = threadIdx.x, ug = t >> 5, kg = t & 31;
  {
    float acc[8][8];
#pragma unroll
    for (int uu = 0; uu < 8; uu++)
#pragma unroll
      for (int j = 0; j < 8; j++) acc[uu][j] = 0.f;
    SCORE_TILE(acc, qsT, Kmat, b, c, ug, kg);
#pragma unroll
    for (int uu = 0; uu < 8; uu++) {
      float mx = den[(size_t)b * 2 * UP + ug * 8 + uu];
      float iv = den[(size_t)b * 2 * UP + UP + ug * 8 + uu];
#pragma unroll
      for (int j = 0; j < 8; j++)
        wl[(ug * 8 + uu) * CKK + kg + 32 * j] = __expf(acc[uu][j] - mx) * iv;
    }
  }
  __syncthreads();
  // phase B: wave w handles 16 u rows, lane = d
  int w = t >> 6, lane = t & 63;
  float acc2[16];
#pragma unroll
  for (int uu = 0; uu < 16; uu++) acc2[uu] = 0.f;
  const float* Vb = V + ((size_t)b * Lv + (size_t)c * CKK) * Dv;
  for (int k4 = 0; k4 < CKK; k4 += 4) {
    float v0 = Vb[(size_t)(k4 + 0) * Dv + lane];
    float v1 = Vb[(size_t)(k4 + 1) * Dv + lane];
    float v2 = Vb[(size_t)(k4 + 2) * Dv + lane];
    float v3 = Vb[(size_t)(k4 + 3) * Dv + lane];
#pragma unroll
    for (int uu = 0; uu < 16; uu++) {
      float4 w4 = *(const float4*)&wl[(w * 16 + uu) * CKK + k4];
      acc2[uu] += w4.x * v0 + w4.y * v1 + w4.z * v2 + w4.w * v3;
    }
  }
#pragma unroll
  for (int uu = 0; uu < 16; uu++)
    ppv[(((size_t)b * NC + c) * UP + w * 16 + uu) * Dv + lane] = acc2[uu];
}

// ============================================================
// cumsum over L: k_cs1 sub-chunk sums, k_cs3 prefix(own) + scan + write
// ============================================================
__global__ __launch_bounds__(256) void k_cs1(const float* __restrict__ V,
                                             float* __restrict__ cs) {
  int b = blockIdx.x >> 4, c4 = blockIdx.x & 15;
  int g = threadIdx.x >> 6, d = threadIdx.x & 63;
  int sub = c4 * 4 + g;
  const float* Vb = V + ((size_t)b * Lv + sub * 64) * Dv + d;
  float acc = 0.f;
  for (int r = 0; r < 64; r++) acc += Vb[(size_t)r * Dv];
  cs[((size_t)b * NSUB + sub) * Dv + d] = acc;
}

__global__ __launch_bounds__(256) void k_cs3(const float* __restrict__ V,
                                             const float* __restrict__ cs,
                                             float* __restrict__ out) {
  int b = blockIdx.x >> 4, c4 = blockIdx.x & 15;
  int g = threadIdx.x >> 6, d = threadIdx.x & 63;
  int sub = c4 * 4 + g;
  // own prefix over preceding sub-chunks (cs is tiny, L2-resident)
  float acc = 0.f;
  for (int s = 0; s < sub; s++) acc += cs[((size_t)b * NSUB + s) * Dv + d];
  const float* Vb = V + ((size_t)b * Lv + sub * 64) * Dv + d;
  float* Ob = out + ((size_t)b * Lv + sub * 64) * Dv + d;
  for (int r = 0; r < 64; r++) {
    acc += Vb[(size_t)r * Dv];
    Ob[(size_t)r * Dv] = acc;
  }
}

// ============================================================
// K10: merge PV partials, scatter into output rows
// ============================================================
__global__ __launch_bounds__(64) void k_upd(const float* __restrict__ ppv,
                                            const int* __restrict__ Mtop,
                                            float* __restrict__ out) {
  int b = blockIdx.x / Uv, u = blockIdx.x % Uv;
  int d = threadIdx.x;
  float s = 0.f;
  for (int c = 0; c < NC; c++)
    s += ppv[(((size_t)b * NC + c) * UP + u) * Dv + d];
  int row = Mtop[b * Uv + u];
  out[((size_t)b * Lv + row) * Dv + d] = s;
}

extern "C" void kernel_launch(void* const* d_in, const int* in_sizes, int n_in,
                              void* d_out, int out_size, void* d_ws, size_t ws_size,
                              hipStream_t stream) {
  (void)in_sizes; (void)n_in; (void)out_size; (void)ws_size;
  const float* Q = (const float*)d_in[0];
  const float* K = (const float*)d_in[1];
  const float* V = (const float*)d_in[2];
  const int* idx = (const int*)d_in[3];
  float* out = (float*)d_out;
  float* wsf = (float*)d_ws;
  float* M   = wsf + OFF_M;
  float* Qr  = wsf + OFF_QR;
  float* pms = wsf + OFF_PMS;
  float* den = wsf + OFF_DEN;
  float* ppv = wsf + OFF_PPV;
  float* cs  = wsf + OFF_CS;
  int* top   = (int*)(wsf + OFF_TOP);

  k_M<<<8192, 256, 0, stream>>>(Q, K, idx, M);
  k_topk<<<Bv, 1024, 0, stream>>>(M, Q, top, Qr);
  k_ms<<<Bv * NC, 192, 0, stream>>>(K, Qr, pms);
  k_den<<<Bv, 64, 0, stream>>>(pms, den);
  k_pv<<<Bv * NC, 192, 0, stream>>>(K, V, Qr, den, ppv);
  k_cs1<<<1024, 256, 0, stream>>>(V, cs);
  k_cs3<<<1024, 256, 0, stream>>>(V, cs, out);
  k_upd<<<Bv * Uv, 64, 0, stream>>>(ppv, top, out);
}

// Round 6
// 575.463 us; speedup vs baseline: 1.6078x; 1.0362x over previous
//
#include <hip/hip_runtime.h>

#define Bv 64
#define Lv 4096
#define Dv 64
#define Uv 45
#define UP 48      // padded u
#define NC 32      // score chunks
#define CKK 128    // keys per chunk (Lv/NC)
#define NJ 4       // CKK/32
#define UPP 52     // padded qsT stride (16B-aligned, 8-way instead of 32-way)
#define NSUB 64    // cumsum sub-chunks of 64 rows

// ---- workspace layout (in floats) ----
#define OFF_M    0
#define SZ_M     (Bv*Lv)
#define OFF_QR   (OFF_M + SZ_M)
#define SZ_QR    (Bv*UP*Dv)
#define OFF_PMS  (OFF_QR + SZ_QR)
#define SZ_PMS   (Bv*NC*2*UP)
#define OFF_DEN  (OFF_PMS + SZ_PMS)
#define SZ_DEN   (Bv*2*UP)
#define OFF_UPD  (OFF_DEN + SZ_DEN)
#define SZ_UPD   (Bv*UP*Dv)
#define OFF_CS   (OFF_UPD + SZ_UPD)
#define SZ_CS    (Bv*NSUB*Dv)
#define OFF_TOP  (OFF_CS + SZ_CS)
#define SZ_TOP   (Bv*Uv)

// ============================================================
// K1: M[b,l] = max_s(q.k_idx) - sum_s(q.k_idx)/L
// w=8 lanes per row; idx in LDS; XCD phase-lock keeps ~2 batches/XCD L2.
// ============================================================
__global__ __launch_bounds__(256) void k_M(const float* __restrict__ Q,
                                           const float* __restrict__ K,
                                           const int* __restrict__ idx,
                                           float* __restrict__ Mout) {
  __shared__ int sidx[32 * Uv];
  int i = blockIdx.x;
  int x = i & 7, j = i >> 3;
  int b = x + 8 * (j >> 7);
  int w = j & 127;
  int t = threadIdx.x;
  for (int p = t; p < 32 * Uv; p += 256) sidx[p] = idx[(w * 32) * Uv + p];
  int g = t >> 3, lane = t & 7;
  int l = w * 32 + g;
  const float4* qr = (const float4*)(Q + ((size_t)b * Lv + l) * Dv + lane * 8);
  float4 q0 = qr[0], q1 = qr[1];
  const char* Kb = (const char*)(K + (size_t)b * Lv * Dv) + lane * 32;
  __syncthreads();
  float mx = -3.0e38f, sm = 0.f;
#pragma unroll 3
  for (int s = 0; s < Uv; s++) {
    int ki = sidx[g * Uv + s];
    const float4* kr = (const float4*)(Kb + (size_t)ki * 256);
    float4 k0 = kr[0], k1 = kr[1];
    float d = q0.x * k0.x + q0.y * k0.y + q0.z * k0.z + q0.w * k0.w
            + q1.x * k1.x + q1.y * k1.y + q1.z * k1.z + q1.w * k1.w;
    d += __shfl_xor(d, 1);
    d += __shfl_xor(d, 2);
    d += __shfl_xor(d, 4);
    mx = fmaxf(mx, d);
    sm += d;
  }
  if (lane == 0) Mout[(size_t)b * Lv + l] = mx - sm * (1.0f / (float)Lv);
}

// ============================================================
// K2: top-45 per batch, register-resident, 1024 threads. Fused qstage.
// ============================================================
__global__ __launch_bounds__(1024) void k_topk(const float* __restrict__ M,
                                               const float* __restrict__ Q,
                                               int* __restrict__ Mtop,
                                               float* __restrict__ Qr) {
  __shared__ float wv[16];
  __shared__ int wi[16];
  __shared__ int win_i_s;
  __shared__ int list[Uv];
  int b = blockIdx.x;
  int t = threadIdx.x;
  const float* Mb = M + (size_t)b * Lv;
  float r0 = Mb[t], r1 = Mb[t + 1024], r2 = Mb[t + 2048], r3 = Mb[t + 3072];
  int wave = t >> 6, lane = t & 63;
  for (int it = 0; it < Uv; it++) {
    float bv = r0; int bi = t;
    if (r1 > bv) { bv = r1; bi = t + 1024; }
    if (r2 > bv) { bv = r2; bi = t + 2048; }
    if (r3 > bv) { bv = r3; bi = t + 3072; }
#pragma unroll
    for (int off = 1; off < 64; off <<= 1) {
      float v2 = __shfl_xor(bv, off);
      int i2 = __shfl_xor(bi, off);
      if (v2 > bv || (v2 == bv && i2 < bi)) { bv = v2; bi = i2; }
    }
    if (lane == 0) { wv[wave] = bv; wi[wave] = bi; }
    __syncthreads();
    if (t < 64) {
      float cv = (lane < 16) ? wv[lane] : -3.0e38f;
      int ci = (lane < 16) ? wi[lane] : (1 << 30);
#pragma unroll
      for (int off = 1; off < 16; off <<= 1) {
        float v2 = __shfl_xor(cv, off);
        int i2 = __shfl_xor(ci, off);
        if (v2 > cv || (v2 == cv && i2 < ci)) { cv = v2; ci = i2; }
      }
      if (lane == 0) { win_i_s = ci; list[it] = ci; }
    }
    __syncthreads();
    int wn = win_i_s;
    if ((wn & 1023) == t) {
      int c = wn >> 10;
      if (c == 0) r0 = -3.0e38f;
      else if (c == 1) r1 = -3.0e38f;
      else if (c == 2) r2 = -3.0e38f;
      else r3 = -3.0e38f;
    }
    __syncthreads();
  }
  if (t < Uv) Mtop[b * Uv + t] = list[t];
  for (int p = t; p < UP * Dv; p += 1024) {
    int u = p >> 6, e = p & 63;
    float v = 0.f;
    if (u < Uv) {
      int row = list[u];
      v = Q[((size_t)b * Lv + row) * Dv + e] * 0.125f;
    }
    Qr[((size_t)b * UP + u) * Dv + e] = v;
  }
}

// ---- stage Qr transposed into LDS (stride UPP) ----
#define STAGE_QST(QS, QR, b)                                        \
  for (int i_ = threadIdx.x; i_ < Dv * UP; i_ += blockDim.x) {      \
    int u_ = i_ >> 6, e_ = i_ & 63;                                 \
    QS[e_ * UPP + u_] = QR[((size_t)(b) * UP + u_) * Dv + e_];      \
  }

// ---- GEMM tile: acc[uu][j] = score(u=ug*8+uu, kk=c*CKK+kg+32*j), NJ j's ----
#define SCORE_TILE(ACC, QS, KMAT, b_, c_, ug_, kg_)                                   \
  {                                                                                    \
    const float* Kb_ = (KMAT) + ((size_t)(b_) * Lv + (size_t)(c_) * CKK + (kg_)) * Dv; \
    for (int e = 0; e < Dv; e += 4) {                                                  \
      float qq[4][8];                                                                  \
      _Pragma("unroll")                                                                \
      for (int e2 = 0; e2 < 4; e2++) {                                                 \
        float4 qa = *(const float4*)&(QS)[(e + e2) * UPP + (ug_) * 8];                 \
        float4 qb = *(const float4*)&(QS)[(e + e2) * UPP + (ug_) * 8 + 4];             \
        qq[e2][0]=qa.x; qq[e2][1]=qa.y; qq[e2][2]=qa.z; qq[e2][3]=qa.w;                \
        qq[e2][4]=qb.x; qq[e2][5]=qb.y; qq[e2][6]=qb.z; qq[e2][7]=qb.w;                \
      }                                                                                \
      _Pragma("unroll")                                                                \
      for (int j = 0; j < NJ; j++) {                                                   \
        float4 kv = *(const float4*)(Kb_ + (size_t)(32 * j) * Dv + e);                 \
        _Pragma("unroll")                                                              \
        for (int uu = 0; uu < 8; uu++)                                                 \
          ACC[uu][j] += qq[0][uu]*kv.x + qq[1][uu]*kv.y + qq[2][uu]*kv.z + qq[3][uu]*kv.w; \
      }                                                                                \
    }                                                                                  \
  }

// ============================================================
// K4: per-chunk max and sum-exp partials (chunk = 128 keys)
// ============================================================
__global__ __launch_bounds__(192) void k_ms(const float* __restrict__ Kmat,
                                            const float* __restrict__ Qr,
                                            float* __restrict__ pms) {
  __shared__ float qsT[Dv * UPP];
  int b = blockIdx.x >> 5, c = blockIdx.x & 31;
  STAGE_QST(qsT, Qr, b);
  __syncthreads();
  int t = threadIdx.x, ug = t >> 5, kg = t & 31;
  float acc[8][NJ];
#pragma unroll
  for (int uu = 0; uu < 8; uu++)
#pragma unroll
    for (int j = 0; j < NJ; j++) acc[uu][j] = 0.f;
  SCORE_TILE(acc, qsT, Kmat, b, c, ug, kg);
#pragma unroll
  for (int uu = 0; uu < 8; uu++) {
    float m = acc[uu][0];
#pragma unroll
    for (int j = 1; j < NJ; j++) m = fmaxf(m, acc[uu][j]);
#pragma unroll
    for (int off = 1; off < 32; off <<= 1) m = fmaxf(m, __shfl_xor(m, off));
    float s = 0.f;
#pragma unroll
    for (int j = 0; j < NJ; j++) s += __expf(acc[uu][j] - m);
#pragma unroll
    for (int off = 1; off < 32; off <<= 1) s += __shfl_xor(s, off);
    if (kg == 0) {
      pms[(((size_t)b * NC + c) * 2 + 0) * UP + ug * 8 + uu] = m;
      pms[(((size_t)b * NC + c) * 2 + 1) * UP + ug * 8 + uu] = s;
    }
  }
}

// ============================================================
// K5: merge chunk partials -> global max + 1/denominator
// ============================================================
__global__ __launch_bounds__(64) void k_den(const float* __restrict__ pms,
                                            float* __restrict__ den) {
  int b = blockIdx.x, u = threadIdx.x;
  if (u >= UP) return;
  float mx = -3.0e38f;
  for (int c = 0; c < NC; c++)
    mx = fmaxf(mx, pms[(((size_t)b * NC + c) * 2 + 0) * UP + u]);
  float d = 0.f;
  for (int c = 0; c < NC; c++)
    d += pms[(((size_t)b * NC + c) * 2 + 1) * UP + u] *
         __expf(pms[(((size_t)b * NC + c) * 2 + 0) * UP + u] - mx);
  den[(size_t)b * 2 * UP + u] = mx;
  den[(size_t)b * 2 * UP + UP + u] = 1.f / d;
}

// ============================================================
// K_zero: zero the atomic accumulation buffer (ws is poisoned each call)
// ============================================================
__global__ __launch_bounds__(256) void k_zero(float4* __restrict__ upd4) {
  upd4[blockIdx.x * 256 + threadIdx.x] = make_float4(0.f, 0.f, 0.f, 0.f);
}

// ============================================================
// K6: recompute scores, softmax weights, PV partial; atomicAdd into upd
// ============================================================
__global__ __launch_bounds__(192) void k_pv(const float* __restrict__ Kmat,
                                            const float* __restrict__ V,
                                            const float* __restrict__ Qr,
                                            const float* __restrict__ den,
                                            float* __restrict__ upd) {
  __shared__ float qsT[Dv * UPP];   // 13.3 KB
  __shared__ float wl[UP * CKK];    // 24 KB
  int b = blockIdx.x >> 5, c = blockIdx.x & 31;
  STAGE_QST(qsT, Qr, b);
  __syncthreads();
  int t = threadIdx.x, ug = t >> 5, kg = t & 31;
  {
    float acc[8][NJ];
#pragma unroll
    for (int uu = 0; uu < 8; uu++)
#pragma unroll
      for (int j = 0; j < NJ; j++) acc[uu][j] = 0.f;
    SCORE_TILE(acc, qsT, Kmat, b, c, ug, kg);
#pragma unroll
    for (int uu = 0; uu < 8; uu++) {
      float mx = den[(size_t)b * 2 * UP + ug * 8 + uu];
      float iv = den[(size_t)b * 2 * UP + UP + ug * 8 + uu];
#pragma unroll
      for (int j = 0; j < NJ; j++)
        wl[(ug * 8 + uu) * CKK + kg + 32 * j] = __expf(acc[uu][j] - mx) * iv;
    }
  }
  __syncthreads();
  // phase B: wave w handles 16 u rows, lane = d
  int w = t >> 6, lane = t & 63;
  float acc2[16];
#pragma unroll
  for (int uu = 0; uu < 16; uu++) acc2[uu] = 0.f;
  const float* Vb = V + ((size_t)b * Lv + (size_t)c * CKK) * Dv;
  for (int k4 = 0; k4 < CKK; k4 += 4) {
    float v0 = Vb[(size_t)(k4 + 0) * Dv + lane];
    float v1 = Vb[(size_t)(k4 + 1) * Dv + lane];
    float v2 = Vb[(size_t)(k4 + 2) * Dv + lane];
    float v3 = Vb[(size_t)(k4 + 3) * Dv + lane];
#pragma unroll
    for (int uu = 0; uu < 16; uu++) {
      float4 w4 = *(const float4*)&wl[(w * 16 + uu) * CKK + k4];
      acc2[uu] += w4.x * v0 + w4.y * v1 + w4.z * v2 + w4.w * v3;
    }
  }
#pragma unroll
  for (int uu = 0; uu < 16; uu++)
    atomicAdd(&upd[((size_t)b * UP + w * 16 + uu) * Dv + lane], acc2[uu]);
}

// ============================================================
// cumsum over L: k_cs1 sub-chunk sums, k_cs3 own-prefix + scan + write
// ============================================================
__global__ __launch_bounds__(256) void k_cs1(const float* __restrict__ V,
                                             float* __restrict__ cs) {
  int b = blockIdx.x >> 4, c4 = blockIdx.x & 15;
  int g = threadIdx.x >> 6, d = threadIdx.x & 63;
  int sub = c4 * 4 + g;
  const float* Vb = V + ((size_t)b * Lv + sub * 64) * Dv + d;
  float acc = 0.f;
  for (int r = 0; r < 64; r++) acc += Vb[(size_t)r * Dv];
  cs[((size_t)b * NSUB + sub) * Dv + d] = acc;
}

__global__ __launch_bounds__(256) void k_cs3(const float* __restrict__ V,
                                             const float* __restrict__ cs,
                                             float* __restrict__ out) {
  int b = blockIdx.x >> 4, c4 = blockIdx.x & 15;
  int g = threadIdx.x >> 6, d = threadIdx.x & 63;
  int sub = c4 * 4 + g;
  float acc = 0.f;
  for (int s = 0; s < sub; s++) acc += cs[((size_t)b * NSUB + s) * Dv + d];
  const float* Vb = V + ((size_t)b * Lv + sub * 64) * Dv + d;
  float* Ob = out + ((size_t)b * Lv + sub * 64) * Dv + d;
  for (int r = 0; r < 64; r++) {
    acc += Vb[(size_t)r * Dv];
    Ob[(size_t)r * Dv] = acc;
  }
}

// ============================================================
// K10: scatter upd rows into output
// ============================================================
__global__ __launch_bounds__(64) void k_upd(const float* __restrict__ upd,
                                            const int* __restrict__ Mtop,
                                            float* __restrict__ out) {
  int b = blockIdx.x / Uv, u = blockIdx.x % Uv;
  int d = threadIdx.x;
  float s = upd[((size_t)b * UP + u) * Dv + d];
  int row = Mtop[b * Uv + u];
  out[((size_t)b * Lv + row) * Dv + d] = s;
}

extern "C" void kernel_launch(void* const* d_in, const int* in_sizes, int n_in,
                              void* d_out, int out_size, void* d_ws, size_t ws_size,
                              hipStream_t stream) {
  (void)in_sizes; (void)n_in; (void)out_size; (void)ws_size;
  const float* Q = (const float*)d_in[0];
  const float* K = (const float*)d_in[1];
  const float* V = (const float*)d_in[2];
  const int* idx = (const int*)d_in[3];
  float* out = (float*)d_out;
  float* wsf = (float*)d_ws;
  float* M   = wsf + OFF_M;
  float* Qr  = wsf + OFF_QR;
  float* pms = wsf + OFF_PMS;
  float* den = wsf + OFF_DEN;
  float* upd = wsf + OFF_UPD;
  float* cs  = wsf + OFF_CS;
  int* top   = (int*)(wsf + OFF_TOP);

  k_M<<<8192, 256, 0, stream>>>(Q, K, idx, M);
  k_topk<<<Bv, 1024, 0, stream>>>(M, Q, top, Qr);
  k_ms<<<Bv * NC, 192, 0, stream>>>(K, Qr, pms);
  k_den<<<Bv, 64, 0, stream>>>(pms, den);
  k_zero<<<(Bv * UP * Dv) / 1024, 256, 0, stream>>>((float4*)upd);
  k_pv<<<Bv * NC, 192, 0, stream>>>(K, V, Qr, den, upd);
  k_cs1<<<1024, 256, 0, stream>>>(V, cs);
  k_cs3<<<1024, 256, 0, stream>>>(V, cs, out);
  k_upd<<<Bv * Uv, 64, 0, stream>>>(upd, top, out);
}

// Round 7
// 528.384 us; speedup vs baseline: 1.7510x; 1.0891x over previous
//
#include <hip/hip_runtime.h>

#define Bv 64
#define Lv 4096
#define Dv 64
#define Uv 45
#define UP 48      // padded u
#define NC 32      // score chunks
#define CKK 128    // keys per chunk (Lv/NC)
#define NJ 4       // CKK/32
#define UPP 52     // padded qsT stride
#define NSUB 128   // cumsum sub-chunks of 32 rows (matches k_M block tiling)

// ---- workspace layout (in floats) ----
#define OFF_M    0
#define SZ_M     (Bv*Lv)
#define OFF_QR   (OFF_M + SZ_M)
#define SZ_QR    (Bv*UP*Dv)
#define OFF_UPD  (OFF_QR + SZ_QR)
#define SZ_UPD   (Bv*UP*Dv)
#define OFF_DEN  (OFF_UPD + SZ_UPD)          // MUST follow UPD (zeroed together)
#define SZ_DEN   (Bv*UP)
#define OFF_CS   (OFF_DEN + SZ_DEN)
#define SZ_CS    (Bv*NSUB*Dv)
#define OFF_TOP  (OFF_CS + SZ_CS)
#define SZ_TOP   (Bv*Uv)
// zero region = UPD+DEN = 199680 floats = 49920 float4 = 195 blocks * 256
#define NZBLK 195

// ============================================================
// K1: M[b,l] = max_s(q.k_idx) - sum_s(q.k_idx)/L
// + fused: 32-row V partial sums (cs1) + zeroing of upd/den.
// w=8 lanes per row; idx in LDS; XCD phase-lock (~2 batches/XCD in L2).
// ============================================================
__global__ __launch_bounds__(256) void k_M(const float* __restrict__ Q,
                                           const float* __restrict__ K,
                                           const float* __restrict__ V,
                                           const int* __restrict__ idx,
                                           float* __restrict__ Mout,
                                           float* __restrict__ cs,
                                           float4* __restrict__ zbuf) {
  __shared__ int sidx[32 * Uv];
  __shared__ float sp[4][Dv];
  int i = blockIdx.x;
  int x = i & 7, j = i >> 3;
  int b = x + 8 * (j >> 7);
  int w = j & 127;
  int t = threadIdx.x;
  // fused zeroing of upd+den (runs every call; ws is re-poisoned)
  if (i < NZBLK) zbuf[(i << 8) + t] = make_float4(0.f, 0.f, 0.f, 0.f);
  for (int p = t; p < 32 * Uv; p += 256) sidx[p] = idx[(w * 32) * Uv + p];
  int g = t >> 3, lane = t & 7;
  int l = w * 32 + g;
  const float4* qr = (const float4*)(Q + ((size_t)b * Lv + l) * Dv + lane * 8);
  float4 q0 = qr[0], q1 = qr[1];
  const char* Kb = (const char*)(K + (size_t)b * Lv * Dv) + lane * 32;
  __syncthreads();
  float mx = -3.0e38f, sm = 0.f;
#pragma unroll 3
  for (int s = 0; s < Uv; s++) {
    int ki = sidx[g * Uv + s];
    const float4* kr = (const float4*)(Kb + (size_t)ki * 256);
    float4 k0 = kr[0], k1 = kr[1];
    float d = q0.x * k0.x + q0.y * k0.y + q0.z * k0.z + q0.w * k0.w
            + q1.x * k1.x + q1.y * k1.y + q1.z * k1.z + q1.w * k1.w;
    d += __shfl_xor(d, 1);
    d += __shfl_xor(d, 2);
    d += __shfl_xor(d, 4);
    mx = fmaxf(mx, d);
    sm += d;
  }
  if (lane == 0) Mout[(size_t)b * Lv + l] = mx - sm * (1.0f / (float)Lv);
  // ---- fused cs1: sum V rows [w*32, w*32+32) -> cs[b][w][d] ----
  int d = t & 63, rq = t >> 6;
  const float* Vb = V + ((size_t)b * Lv + w * 32 + rq * 8) * Dv + d;
  float a = 0.f;
#pragma unroll
  for (int r = 0; r < 8; r++) a += Vb[(size_t)r * Dv];
  sp[rq][d] = a;
  __syncthreads();
  if (t < 64) cs[((size_t)b * NSUB + w) * Dv + t] =
      sp[0][t] + sp[1][t] + sp[2][t] + sp[3][t];
}

// ============================================================
// K2: top-45 per batch, register-resident, 1024 threads. Fused qstage.
// ============================================================
__global__ __launch_bounds__(1024) void k_topk(const float* __restrict__ M,
                                               const float* __restrict__ Q,
                                               int* __restrict__ Mtop,
                                               float* __restrict__ Qr) {
  __shared__ float wv[16];
  __shared__ int wi[16];
  __shared__ int win_i_s;
  __shared__ int list[Uv];
  int b = blockIdx.x;
  int t = threadIdx.x;
  const float* Mb = M + (size_t)b * Lv;
  float r0 = Mb[t], r1 = Mb[t + 1024], r2 = Mb[t + 2048], r3 = Mb[t + 3072];
  int wave = t >> 6, lane = t & 63;
  for (int it = 0; it < Uv; it++) {
    float bv = r0; int bi = t;
    if (r1 > bv) { bv = r1; bi = t + 1024; }
    if (r2 > bv) { bv = r2; bi = t + 2048; }
    if (r3 > bv) { bv = r3; bi = t + 3072; }
#pragma unroll
    for (int off = 1; off < 64; off <<= 1) {
      float v2 = __shfl_xor(bv, off);
      int i2 = __shfl_xor(bi, off);
      if (v2 > bv || (v2 == bv && i2 < bi)) { bv = v2; bi = i2; }
    }
    if (lane == 0) { wv[wave] = bv; wi[wave] = bi; }
    __syncthreads();
    if (t < 64) {
      float cv = (lane < 16) ? wv[lane] : -3.0e38f;
      int ci = (lane < 16) ? wi[lane] : (1 << 30);
#pragma unroll
      for (int off = 1; off < 16; off <<= 1) {
        float v2 = __shfl_xor(cv, off);
        int i2 = __shfl_xor(ci, off);
        if (v2 > cv || (v2 == cv && i2 < ci)) { cv = v2; ci = i2; }
      }
      if (lane == 0) { win_i_s = ci; list[it] = ci; }
    }
    __syncthreads();
    int wn = win_i_s;
    if ((wn & 1023) == t) {
      int c = wn >> 10;
      if (c == 0) r0 = -3.0e38f;
      else if (c == 1) r1 = -3.0e38f;
      else if (c == 2) r2 = -3.0e38f;
      else r3 = -3.0e38f;
    }
    __syncthreads();
  }
  if (t < Uv) Mtop[b * Uv + t] = list[t];
  for (int p = t; p < UP * Dv; p += 1024) {
    int u = p >> 6, e = p & 63;
    float v = 0.f;
    if (u < Uv) {
      int row = list[u];
      v = Q[((size_t)b * Lv + row) * Dv + e] * 0.125f;
    }
    Qr[((size_t)b * UP + u) * Dv + e] = v;
  }
}

// ---- stage Qr transposed into LDS (stride UPP) ----
#define STAGE_QST(QS, QR, b)                                        \
  for (int i_ = threadIdx.x; i_ < Dv * UP; i_ += blockDim.x) {      \
    int u_ = i_ >> 6, e_ = i_ & 63;                                 \
    QS[e_ * UPP + u_] = QR[((size_t)(b) * UP + u_) * Dv + e_];      \
  }

// ---- GEMM tile: acc[uu][j] = score(u=ug*8+uu, kk=c*CKK+kg+32*j) ----
#define SCORE_TILE(ACC, QS, KMAT, b_, c_, ug_, kg_)                                   \
  {                                                                                    \
    const float* Kb_ = (KMAT) + ((size_t)(b_) * Lv + (size_t)(c_) * CKK + (kg_)) * Dv; \
    for (int e = 0; e < Dv; e += 4) {                                                  \
      float qq[4][8];                                                                  \
      _Pragma("unroll")                                                                \
      for (int e2 = 0; e2 < 4; e2++) {                                                 \
        float4 qa = *(const float4*)&(QS)[(e + e2) * UPP + (ug_) * 8];                 \
        float4 qb = *(const float4*)&(QS)[(e + e2) * UPP + (ug_) * 8 + 4];             \
        qq[e2][0]=qa.x; qq[e2][1]=qa.y; qq[e2][2]=qa.z; qq[e2][3]=qa.w;                \
        qq[e2][4]=qb.x; qq[e2][5]=qb.y; qq[e2][6]=qb.z; qq[e2][7]=qb.w;                \
      }                                                                                \
      _Pragma("unroll")                                                                \
      for (int j = 0; j < NJ; j++) {                                                   \
        float4 kv = *(const float4*)(Kb_ + (size_t)(32 * j) * Dv + e);                 \
        _Pragma("unroll")                                                              \
        for (int uu = 0; uu < 8; uu++)                                                 \
          ACC[uu][j] += qq[0][uu]*kv.x + qq[1][uu]*kv.y + qq[2][uu]*kv.z + qq[3][uu]*kv.w; \
      }                                                                                  \
    }                                                                                  \
  }

// ============================================================
// K6: fused scores -> exp (no max-sub; scores bounded ~|6|) -> den partial
//     -> PV partial; atomicAdd into upd/den.
// ============================================================
__global__ __launch_bounds__(192) void k_pv(const float* __restrict__ Kmat,
                                            const float* __restrict__ V,
                                            const float* __restrict__ Qr,
                                            float* __restrict__ upd,
                                            float* __restrict__ den) {
  __shared__ float qsT[Dv * UPP];   // 13.3 KB
  __shared__ float wl[UP * CKK];    // 24 KB
  int b = blockIdx.x >> 5, c = blockIdx.x & 31;
  STAGE_QST(qsT, Qr, b);
  __syncthreads();
  int t = threadIdx.x, ug = t >> 5, kg = t & 31;
  {
    float acc[8][NJ];
#pragma unroll
    for (int uu = 0; uu < 8; uu++)
#pragma unroll
      for (int j = 0; j < NJ; j++) acc[uu][j] = 0.f;
    SCORE_TILE(acc, qsT, Kmat, b, c, ug, kg);
#pragma unroll
    for (int uu = 0; uu < 8; uu++) {
      float dsum = 0.f;
#pragma unroll
      for (int j = 0; j < NJ; j++) {
        float wgt = __expf(acc[uu][j]);
        wl[(ug * 8 + uu) * CKK + kg + 32 * j] = wgt;
        dsum += wgt;
      }
#pragma unroll
      for (int off = 1; off < 32; off <<= 1) dsum += __shfl_xor(dsum, off);
      if (kg == 0) atomicAdd(&den[b * UP + ug * 8 + uu], dsum);
    }
  }
  __syncthreads();
  // phase B: wave w handles 16 u rows, lane = d
  int w = t >> 6, lane = t & 63;
  float acc2[16];
#pragma unroll
  for (int uu = 0; uu < 16; uu++) acc2[uu] = 0.f;
  const float* Vb = V + ((size_t)b * Lv + (size_t)c * CKK) * Dv;
  for (int k4 = 0; k4 < CKK; k4 += 4) {
    float v0 = Vb[(size_t)(k4 + 0) * Dv + lane];
    float v1 = Vb[(size_t)(k4 + 1) * Dv + lane];
    float v2 = Vb[(size_t)(k4 + 2) * Dv + lane];
    float v3 = Vb[(size_t)(k4 + 3) * Dv + lane];
#pragma unroll
    for (int uu = 0; uu < 16; uu++) {
      float4 w4 = *(const float4*)&wl[(w * 16 + uu) * CKK + k4];
      acc2[uu] += w4.x * v0 + w4.y * v1 + w4.z * v2 + w4.w * v3;
    }
  }
#pragma unroll
  for (int uu = 0; uu < 16; uu++)
    atomicAdd(&upd[((size_t)b * UP + w * 16 + uu) * Dv + lane], acc2[uu]);
}

// ============================================================
// cumsum finish: own-prefix over 32-row sub-sums + scan + write
// ============================================================
__global__ __launch_bounds__(256) void k_cs3(const float* __restrict__ V,
                                             const float* __restrict__ cs,
                                             float* __restrict__ out) {
  int b = blockIdx.x >> 5, c4 = blockIdx.x & 31;
  int g = threadIdx.x >> 6, d = threadIdx.x & 63;
  int sub = c4 * 4 + g;
  float acc = 0.f;
  for (int s = 0; s < sub; s++) acc += cs[((size_t)b * NSUB + s) * Dv + d];
  const float* Vb = V + ((size_t)b * Lv + sub * 32) * Dv + d;
  float* Ob = out + ((size_t)b * Lv + sub * 32) * Dv + d;
  for (int r = 0; r < 32; r++) {
    acc += Vb[(size_t)r * Dv];
    Ob[(size_t)r * Dv] = acc;
  }
}

// ============================================================
// K10: normalize (1/den) + scatter upd rows into output
// ============================================================
__global__ __launch_bounds__(64) void k_upd(const float* __restrict__ upd,
                                            const float* __restrict__ den,
                                            const int* __restrict__ Mtop,
                                            float* __restrict__ out) {
  int b = blockIdx.x / Uv, u = blockIdx.x % Uv;
  int d = threadIdx.x;
  float inv = 1.0f / den[b * UP + u];
  float s = upd[((size_t)b * UP + u) * Dv + d] * inv;
  int row = Mtop[b * Uv + u];
  out[((size_t)b * Lv + row) * Dv + d] = s;
}

extern "C" void kernel_launch(void* const* d_in, const int* in_sizes, int n_in,
                              void* d_out, int out_size, void* d_ws, size_t ws_size,
                              hipStream_t stream) {
  (void)in_sizes; (void)n_in; (void)out_size; (void)ws_size;
  const float* Q = (const float*)d_in[0];
  const float* K = (const float*)d_in[1];
  const float* V = (const float*)d_in[2];
  const int* idx = (const int*)d_in[3];
  float* out = (float*)d_out;
  float* wsf = (float*)d_ws;
  float* M   = wsf + OFF_M;
  float* Qr  = wsf + OFF_QR;
  float* upd = wsf + OFF_UPD;
  float* den = wsf + OFF_DEN;
  float* cs  = wsf + OFF_CS;
  int* top   = (int*)(wsf + OFF_TOP);

  k_M<<<8192, 256, 0, stream>>>(Q, K, V, idx, M, cs, (float4*)upd);
  k_topk<<<Bv, 1024, 0, stream>>>(M, Q, top, Qr);
  k_pv<<<Bv * NC, 192, 0, stream>>>(K, V, Qr, upd, den);
  k_cs3<<<Bv * 32, 256, 0, stream>>>(V, cs, out);
  k_upd<<<Bv * Uv, 64, 0, stream>>>(upd, den, top, out);
}